// Round 14
// baseline (53.335 us; speedup 1.0000x reference)
//
#include <hip/hip_runtime.h>
#include <hip/hip_bf16.h>

#define BATCH 4
#define SEQ   4096
#define DIN   768
#define DOUT  64

typedef __attribute__((ext_vector_type(4))) float f32x4;
typedef __attribute__((ext_vector_type(8))) short short8;
typedef __attribute__((ext_vector_type(4))) short short4v;

#define QSCALE 0.18033688011112043f  /* 0.125 * log2(e) */

static __device__ __forceinline__ unsigned short f2bf(float f) {
    union { float f; unsigned u; } un; un.f = f;
    unsigned r = un.u + 0x7FFF + ((un.u >> 16) & 1);
    return (unsigned short)(r >> 16);
}
static __device__ __forceinline__ float bf2f(unsigned short h) {
    union { unsigned u; float f; } un; un.u = ((unsigned)h) << 16;
    return un.f;
}

// ---------------------------------------------------------------------------
// Kernel 0 (v2, unchanged): weights -> B-fragment order.
// ---------------------------------------------------------------------------
__global__ void wprep_kernel(const float* __restrict__ wq,
                             const float* __restrict__ wk,
                             const float* __restrict__ wv,
                             unsigned short* __restrict__ wF) {
    __shared__ float lds[64][65];
    int o = blockIdx.x / 12, kt = blockIdx.x % 12;
    const float* w = (o == 0) ? wq : (o == 1) ? wk : wv;
    int tid = threadIdx.x;
    int k0 = kt * 64;
    #pragma unroll
    for (int i = 0; i < 16; ++i) {
        int flat = tid + i * 256;
        int kl = flat >> 6, n = flat & 63;
        lds[kl][n] = w[(k0 + kl) * 64 + n];
    }
    __syncthreads();
    int lane = tid & 63;
    int m = lane & 15, g = lane >> 4;
    #pragma unroll
    for (int i = 0; i < 2; ++i) {
        int f = i * 4 + (tid >> 6);
        int t = f >> 1, kcl = f & 1;
        int kc = kt * 2 + kcl;
        int nc = o * 4 + t;
        short8 v;
        #pragma unroll
        for (int j = 0; j < 8; ++j)
            v[j] = (short)f2bf(lds[kcl * 32 + g * 8 + j][t * 16 + m]);
        *(short8*)&wF[(size_t)(nc * 24 + kc) * 512 + lane * 8] = v;
    }
}

// ---------------------------------------------------------------------------
// Kernel 1 (v8, unchanged): QKV projection, fragment-order I/O, 32 rows/blk.
// ---------------------------------------------------------------------------
__global__ void __launch_bounds__(256) proj_kernel(
        const float* __restrict__ x,
        const float* __restrict__ bq,
        const float* __restrict__ bk,
        const float* __restrict__ bv,
        const unsigned short* __restrict__ wF,
        unsigned short* __restrict__ Qf,
        unsigned short* __restrict__ Kf,
        unsigned short* __restrict__ Vf) {
    __shared__ __align__(16) unsigned short xs[32][776];   // 48.5 KB
    __shared__ unsigned short tr[4][16][24];               // 3 KB

    int tid = threadIdx.x;
    int w = tid >> 6;
    int lane = tid & 63;
    int m = lane & 15, g = lane >> 4;
    int r0 = blockIdx.x * 32;

    {
        const float* xbase = x + (size_t)r0 * DIN;
        #pragma unroll
        for (int i = 0; i < 24; ++i) {
            int flat4 = tid + i * 256;
            int row = flat4 / 192;
            int c4 = flat4 - row * 192;
            float4 v = *(const float4*)(xbase + (size_t)row * DIN + c4 * 4);
            short4v sv;
            sv[0] = (short)f2bf(v.x); sv[1] = (short)f2bf(v.y);
            sv[2] = (short)f2bf(v.z); sv[3] = (short)f2bf(v.w);
            *(short4v*)&xs[row][c4 * 4] = sv;
        }
    }
    __syncthreads();

    f32x4 acc[2][3];
    #pragma unroll
    for (int st = 0; st < 2; ++st)
        #pragma unroll
        for (int t = 0; t < 3; ++t) acc[st][t] = (f32x4){0.f, 0.f, 0.f, 0.f};

    for (int kc = 0; kc < 24; ++kc) {
        short8 af0 = *(const short8*)&xs[m][kc * 32 + g * 8];
        short8 af1 = *(const short8*)&xs[16 + m][kc * 32 + g * 8];
        #pragma unroll
        for (int tt = 0; tt < 3; ++tt) {
            int nc = w * 3 + tt;
            short8 bfrg = *(const short8*)(wF + (size_t)(nc * 24 + kc) * 512 + lane * 8);
            acc[0][tt] = __builtin_amdgcn_mfma_f32_16x16x32_bf16(af0, bfrg, acc[0][tt], 0, 0, 0);
            acc[1][tt] = __builtin_amdgcn_mfma_f32_16x16x32_bf16(af1, bfrg, acc[1][tt], 0, 0, 0);
        }
    }

    int b2 = r0 >> 12;
    int s = (r0 & 4095) >> 5;
    #pragma unroll
    for (int st = 0; st < 2; ++st) {
        #pragma unroll
        for (int tt = 0; tt < 3; ++tt) {
            int nc = w * 3 + tt;
            int o = nc >> 2;
            int t = nc & 3;
            const float* bias_p = (o == 0) ? bq : (o == 1) ? bk : bv;
            float bias = bias_p[t * 16 + m];
            #pragma unroll
            for (int r = 0; r < 4; ++r) {
                float val = acc[st][tt][r] + bias;
                if (o == 0) val *= QSCALE;
                tr[w][g * 4 + r][m] = f2bf(val);
            }
            if (o < 2) {
                if (g < 2) {
                    short8 v8;
                    #pragma unroll
                    for (int j = 0; j < 8; ++j) v8[j] = (short)tr[w][m][g * 8 + j];
                    unsigned short* dst = (o == 0) ? Qf : Kf;
                    int c = t >> 1;
                    *(short8*)&dst[(size_t)((blockIdx.x * 2 + st) * 2 + c) * 512
                                   + (((t & 1) * 2 + g) * 16 + m) * 8] = v8;
                }
            } else {
                if (g < 2) {
                    short8 v8;
                    #pragma unroll
                    for (int j = 0; j < 8; ++j) v8[j] = (short)tr[w][g * 8 + j][m];
                    *(short8*)&Vf[((size_t)(b2 * 128 + s) * 4 + t) * 512
                                  + ((st * 2 + g) * 16 + m) * 8] = v8;
                }
            }
        }
    }
}

// ---------------------------------------------------------------------------
// Kernel 2 (v8): causal flash attention with COMPLEMENTARY Q-TILE PAIRING.
// Block j handles 16-row q-tiles qt = j>>2 and 255-qt (batch = j&3).
// Combined causal work nsteps(qt)+nsteps(255-qt) ~ 129 steps is IDENTICAL
// for every block -> perfect CU load balance regardless of dispatch mapping
// (round-13 analysis: worst CU had ~1.5x avg work under depth-sorted blocks).
// rt0 = shallow tile (drops out after its diagonal), rt1 = deep tile.
// Same inner body, VGPR, LDS as round-13 (launch_bounds(512,2)).
// ---------------------------------------------------------------------------
__global__ void __launch_bounds__(512, 2) attn_kernel(
        const unsigned short* __restrict__ Qf,
        const unsigned short* __restrict__ Kf,
        const unsigned short* __restrict__ Vf,
        float* __restrict__ out) {
    __shared__ __align__(16) unsigned short P_lds[8][32][36];
    __shared__ __align__(16) unsigned short pacc[8][16][68];
    __shared__ float pm[8][16];
    __shared__ float pl[8][16];

    int j = blockIdx.x;
    int b = j & 3;
    int qt = j >> 2;                       // 0..127
    int base0 = qt * 16;                   // shallow tile rows
    int base1 = (255 - qt) * 16;           // deep tile rows
    int ns0 = (qt + 2) >> 1;               // ceil((qt*16+16)/32)
    int ns1 = (257 - qt) >> 1;             // ceil(((255-qt)*16+16)/32)
    int tid = threadIdx.x;
    int w = tid >> 6;
    int lane = tid & 63;
    int m = lane & 15, g = lane >> 4;

    // Q frags for both tiles (fragment-order, contiguous 2KB each)
    const unsigned short* Q0 = Qf + (size_t)(b * 256 + qt) * 1024 + lane * 8;
    const unsigned short* Q1 = Qf + (size_t)(b * 256 + 255 - qt) * 1024 + lane * 8;
    short8 qf[2][2];
    qf[0][0] = *(const short8*)(Q0);
    qf[0][1] = *(const short8*)(Q0 + 512);
    qf[1][0] = *(const short8*)(Q1);
    qf[1][1] = *(const short8*)(Q1 + 512);

    short8 onesB = (short8){0,0,0,0,0,0,0,0};
    if (m == 0) {
        #pragma unroll
        for (int jj = 0; jj < 8; ++jj) onesB[jj] = (short)0x3F80;
    }

    f32x4 acc[2][5];
    #pragma unroll
    for (int rt = 0; rt < 2; ++rt)
        #pragma unroll
        for (int t = 0; t < 5; ++t) acc[rt][t] = (f32x4){0.f, 0.f, 0.f, 0.f};
    float mrun[2][4];
    #pragma unroll
    for (int rt = 0; rt < 2; ++rt)
        #pragma unroll
        for (int r = 0; r < 4; ++r) mrun[rt][r] = -INFINITY;

    const unsigned short* Kbase = Kf + (size_t)(b * 256) * 1024 + lane * 8;
    const unsigned short* Vbase = Vf + (size_t)(b * 128) * 2048 + lane * 8;

    for (int s = w; s < ns1; s += 8) {
        int kv0 = s * 32;
        short8 kf[4];
        kf[0] = *(const short8*)(Kbase + (size_t)s * 2048);
        kf[1] = *(const short8*)(Kbase + (size_t)s * 2048 + 512);
        kf[2] = *(const short8*)(Kbase + (size_t)s * 2048 + 1024);
        kf[3] = *(const short8*)(Kbase + (size_t)s * 2048 + 1536);
        short8 vcur[4];
        #pragma unroll
        for (int t = 0; t < 4; ++t)
            vcur[t] = *(const short8*)(Vbase + (size_t)s * 2048 + t * 512);

        #pragma unroll
        for (int rt = 0; rt < 2; ++rt) {
            if (rt == 0 && s >= ns0) continue;   // shallow tile done
            int qbase = (rt == 0) ? base0 : base1;
            bool lastd = (s == ((rt == 0) ? ns0 : ns1) - 1);

            f32x4 sc[2];
            sc[0] = (f32x4){0.f, 0.f, 0.f, 0.f};
            sc[1] = (f32x4){0.f, 0.f, 0.f, 0.f};
            sc[0] = __builtin_amdgcn_mfma_f32_16x16x32_bf16(qf[rt][0], kf[0], sc[0], 0, 0, 0);
            sc[0] = __builtin_amdgcn_mfma_f32_16x16x32_bf16(qf[rt][1], kf[1], sc[0], 0, 0, 0);
            sc[1] = __builtin_amdgcn_mfma_f32_16x16x32_bf16(qf[rt][0], kf[2], sc[1], 0, 0, 0);
            sc[1] = __builtin_amdgcn_mfma_f32_16x16x32_bf16(qf[rt][1], kf[3], sc[1], 0, 0, 0);

            if (lastd) {
                #pragma unroll
                for (int tt = 0; tt < 2; ++tt)
                    #pragma unroll
                    for (int r = 0; r < 4; ++r)
                        if (kv0 + tt * 16 + m > qbase + g * 4 + r) sc[tt][r] = -INFINITY;
            }

            bool need = false;
            #pragma unroll
            for (int r = 0; r < 4; ++r) {
                float th = mrun[rt][r] + 8.0f;
                need = need | (sc[0][r] > th) | (sc[1][r] > th);
            }
            if (__any(need)) {
                float rmax[4];
                #pragma unroll
                for (int r = 0; r < 4; ++r) rmax[r] = fmaxf(sc[0][r], sc[1][r]);
                #pragma unroll
                for (int msk = 1; msk <= 8; msk <<= 1)
                    #pragma unroll
                    for (int r = 0; r < 4; ++r)
                        rmax[r] = fmaxf(rmax[r], __shfl_xor(rmax[r], msk));
                #pragma unroll
                for (int r = 0; r < 4; ++r) {
                    float mnew = fmaxf(mrun[rt][r], rmax[r]);
                    float alpha = __builtin_amdgcn_exp2f(mrun[rt][r] - mnew);
                    mrun[rt][r] = mnew;
                    #pragma unroll
                    for (int t = 0; t < 5; ++t) acc[rt][t][r] *= alpha;
                }
            }

            #pragma unroll
            for (int tt = 0; tt < 2; ++tt)
                #pragma unroll
                for (int r = 0; r < 4; ++r)
                    P_lds[w][rt * 16 + g * 4 + r][tt * 16 + m] =
                        f2bf(__builtin_amdgcn_exp2f(sc[tt][r] - mrun[rt][r]));
            short8 pa = *(const short8*)&P_lds[w][rt * 16 + m][g * 8];

            #pragma unroll
            for (int t = 0; t < 4; ++t)
                acc[rt][t] = __builtin_amdgcn_mfma_f32_16x16x32_bf16(pa, vcur[t], acc[rt][t], 0, 0, 0);
            acc[rt][4] = __builtin_amdgcn_mfma_f32_16x16x32_bf16(pa, onesB, acc[rt][4], 0, 0, 0);
        }
    }

    #pragma unroll
    for (int rt = 0; rt < 2; ++rt) {
        int qbase = (rt == 0) ? base0 : base1;
        if (m == 0) {
            #pragma unroll
            for (int r = 0; r < 4; ++r) {
                pm[w][g * 4 + r] = mrun[rt][r];
                pl[w][g * 4 + r] = acc[rt][4][r];
            }
        }
        #pragma unroll
        for (int t = 0; t < 4; ++t)
            #pragma unroll
            for (int r = 0; r < 4; ++r)
                pacc[w][g * 4 + r][t * 16 + m] = f2bf(acc[rt][t][r]);
        __syncthreads();

        if (tid < 256) {
            int row = tid >> 4;
            int c4 = (tid & 15) * 4;
            float mmax = pm[0][row];
            #pragma unroll
            for (int w2 = 1; w2 < 8; ++w2) mmax = fmaxf(mmax, pm[w2][row]);
            float lt = 0.f;
            float o0 = 0.f, o1 = 0.f, o2 = 0.f, o3 = 0.f;
            #pragma unroll
            for (int w2 = 0; w2 < 8; ++w2) {
                float sc2 = __builtin_amdgcn_exp2f(pm[w2][row] - mmax);
                lt += pl[w2][row] * sc2;
                short4v pa4 = *(const short4v*)&pacc[w2][row][c4];
                o0 += bf2f((unsigned short)pa4[0]) * sc2;
                o1 += bf2f((unsigned short)pa4[1]) * sc2;
                o2 += bf2f((unsigned short)pa4[2]) * sc2;
                o3 += bf2f((unsigned short)pa4[3]) * sc2;
            }
            float invl = 1.0f / lt;
            float4 res = make_float4(o0 * invl, o1 * invl, o2 * invl, o3 * invl);
            *(float4*)&out[(size_t)(b * SEQ + qbase + row) * DOUT + c4] = res;
        }
        __syncthreads();
    }
}

// ---------------------------------------------------------------------------
extern "C" void kernel_launch(void* const* d_in, const int* in_sizes, int n_in,
                              void* d_out, int out_size, void* d_ws, size_t ws_size,
                              hipStream_t stream) {
    const float* x  = (const float*)d_in[0];
    const float* wq = (const float*)d_in[1];
    const float* bq = (const float*)d_in[2];
    const float* wk = (const float*)d_in[3];
    const float* bk = (const float*)d_in[4];
    const float* wv = (const float*)d_in[5];
    const float* bv = (const float*)d_in[6];
    float* out = (float*)d_out;

    char* ws = (char*)d_ws;
    unsigned short* wF = (unsigned short*)ws;                       // 294912 B
    unsigned short* Qf = (unsigned short*)(ws + 294912);            // 2 MB
    unsigned short* Kf = (unsigned short*)(ws + 294912 + 2097152);  // 2 MB
    unsigned short* Vf = (unsigned short*)(ws + 294912 + 4194304);  // 2 MB

    wprep_kernel<<<36, 256, 0, stream>>>(wq, wk, wv, wF);
    proj_kernel<<<512, 256, 0, stream>>>(x, bq, bk, bv, wF, Qf, Kf, Vf);
    attn_kernel<<<512, 512, 0, stream>>>(Qf, Kf, Vf, out);
}